// Round 15
// baseline (36.378 us; speedup 1.0000x reference)
//
#include <hip/hip_runtime.h>

#define B 8
#define T 128
#define U 64
#define V 512
#define ROWS (T + 2)
#define PADK 520               // bf16 elems per LDS P-row (512+8 pad); PADK/8=65
#define LN2 0.6931471805599453f

typedef __attribute__((ext_vector_type(8))) short bf8v;   // 8 bf16 (4 VGPR)
typedef __attribute__((ext_vector_type(4))) float f4v;    // MFMA accumulator

// ---- DPP wave-64 helpers ---------------------------------------------------
template<int CTRL, int ROWM>
__device__ __forceinline__ float dpp_movf(float x, int old_bits) {
    int r = __builtin_amdgcn_update_dpp(old_bits, __builtin_bit_cast(int, x),
                                        CTRL, ROWM, 0xF, false);
    return __builtin_bit_cast(float, r);
}
__device__ __forceinline__ float wave_max63(float x) {
    const int NI = (int)0xff800000u;   // -inf
    x = fmaxf(x, dpp_movf<0x111, 0xF>(x, NI));
    x = fmaxf(x, dpp_movf<0x112, 0xF>(x, NI));
    x = fmaxf(x, dpp_movf<0x114, 0xF>(x, NI));
    x = fmaxf(x, dpp_movf<0x118, 0xF>(x, NI));
    x = fmaxf(x, dpp_movf<0x142, 0xA>(x, NI));
    x = fmaxf(x, dpp_movf<0x143, 0xC>(x, NI));
    return x;
}
__device__ __forceinline__ float rdlane(float x, int lane) {
    return __builtin_bit_cast(float,
        __builtin_amdgcn_readlane(__builtin_bit_cast(int, x), lane));
}
__device__ __forceinline__ float dpp_shr1(float x) {   // lane u <- u-1; lane0 <- 0
    int r = __builtin_amdgcn_update_dpp(0, __builtin_bit_cast(int, x),
                                        0x138, 0xF, 0xF, false); // wave_shr:1
    return __builtin_bit_cast(float, r);
}

// ---- bf16 split helpers (RNE) ----------------------------------------------
__device__ __forceinline__ short f2bf(float x) {
    unsigned b = __builtin_bit_cast(unsigned, x);
    unsigned r = (b + 0x7FFFu + ((b >> 16) & 1u)) >> 16;
    return (short)r;
}
__device__ __forceinline__ float bf2f(short h) {
    return __builtin_bit_cast(float, ((unsigned)(unsigned short)h) << 16);
}

// ---------------------------------------------------------------------------
// K1 (MFMA lp): grid 32 = (b:8) x (th:2 t-half) x (uh:2 u-half), 512 threads.
// Build Pexp hi/lo (32 u-rows) in LDS; S = Eexp·Pexp^T via
// mfma_f32_16x16x32_bf16 x3 (hh,hl,lh — verified exact in R13/R14);
// epilogue writes blankP/labelP probabilities (R12 layout, unchanged).
// No max-subtract (N(0,1) inputs — verified safe).  No wave reductions at all.
// ---------------------------------------------------------------------------
__global__ __launch_bounds__(512) void lp_kernel(
    const float* __restrict__ em, const float* __restrict__ pr,
    const int* __restrict__ labels,
    float* __restrict__ blankP, float* __restrict__ labelP)
{
    __shared__ __align__(16) short Ph[32 * PADK];   // 33280 B
    __shared__ __align__(16) short Pl[32 * PADK];   // 33280 B
    __shared__ float Ee0s[64], Pp0s[32], Ppls[32];
    __shared__ int   lbls[32];

    const int bid  = blockIdx.x;
    const int uh   = bid & 1;
    const int th   = (bid >> 1) & 1;
    const int b    = bid >> 2;
    const int tid  = threadIdx.x;
    const int lane = tid & 63;
    const int w    = tid >> 6;            // 0..7

    // ---- fp32-precise numerator tables
    if (tid < 64)
        Ee0s[tid] = __expf(em[((size_t)b * T + th * 64 + tid) * V]);
    if (tid < 32) {
        const int u = uh * 32 + tid;
        Pp0s[tid] = __expf(pr[((size_t)b * U + u) * V]);
        if (u < U - 1) {
            const int lb = labels[b * (U - 1) + u];
            lbls[tid] = lb;
            Ppls[tid] = __expf(pr[((size_t)b * U + u) * V + lb]);
        } else {
            lbls[tid] = 0;
            Ppls[tid] = 0.0f;
        }
    }

    // ---- build Pexp (32 rows) split hi/lo
    for (int idx = tid; idx < 32 * 64; idx += 512) {
        const int ul = idx >> 6, c = idx & 63;
        const int u  = uh * 32 + ul;
        const float* prow = pr + ((size_t)b * U + u) * V + c * 8;
        const float4 f0 = ((const float4*)prow)[0];
        const float4 f1 = ((const float4*)prow)[1];
        const float e[8] = {f0.x, f0.y, f0.z, f0.w, f1.x, f1.y, f1.z, f1.w};
        bf8v hi, lo;
        #pragma unroll
        for (int j = 0; j < 8; ++j) {
            const float x = __expf(e[j]);
            const short h = f2bf(x);
            hi[j] = h;
            lo[j] = f2bf(x - bf2f(h));
        }
        ((bf8v*)Ph)[ul * (PADK / 8) + c] = hi;
        ((bf8v*)Pl)[ul * (PADK / 8) + c] = lo;
    }
    __syncthreads();

    // ---- GEMM: wave w -> M-tile mt = w>>1 (16 t's), N-tile ntl = w&1 (16 u's)
    const int mt   = w >> 1;            // 0..3
    const int ntl  = w & 1;             // 0..1
    const int arow = lane & 15;
    const int kb   = (lane >> 4) * 8;

    f4v acc = (f4v){0.f, 0.f, 0.f, 0.f};
    const int t_load = th * 64 + mt * 16 + arow;
    const float* erow = em + ((size_t)b * T + t_load) * V;
    const int bu = ntl * 16 + arow;     // B-frag col (local u)

    #pragma unroll 4
    for (int ks = 0; ks < 16; ++ks) {
        const int k0 = ks * 32 + kb;
        const float4 f0 = ((const float4*)(erow + k0))[0];
        const float4 f1 = ((const float4*)(erow + k0))[1];
        const float e[8] = {f0.x, f0.y, f0.z, f0.w, f1.x, f1.y, f1.z, f1.w};
        bf8v ah, al;
        #pragma unroll
        for (int j = 0; j < 8; ++j) {
            const float x = __expf(e[j]);
            const short h = f2bf(x);
            ah[j] = h;
            al[j] = f2bf(x - bf2f(h));
        }
        const bf8v bh = ((const bf8v*)Ph)[bu * (PADK / 8) + k0 / 8];
        const bf8v bl = ((const bf8v*)Pl)[bu * (PADK / 8) + k0 / 8];
        acc = __builtin_amdgcn_mfma_f32_16x16x32_bf16(ah, bh, acc, 0, 0, 0);
        acc = __builtin_amdgcn_mfma_f32_16x16x32_bf16(ah, bl, acc, 0, 0, 0);
        acc = __builtin_amdgcn_mfma_f32_16x16x32_bf16(al, bh, acc, 0, 0, 0);
    }

    // ---- epilogue: C/D col = lane&15, row = (lane>>4)*4 + r  (verified map)
    const int ccol  = lane & 15;
    const int crow0 = (lane >> 4) * 4;
    const int ul    = ntl * 16 + ccol;          // local u
    const int u     = uh * 32 + ul;
    #pragma unroll
    for (int r = 0; r < 4; ++r) {
        const int tl = mt * 16 + crow0 + r;     // t within half
        const int t  = th * 64 + tl;
        const float inv = 1.0f / acc[r];
        const size_t o = ((size_t)b * T + t) * U + u;
        blankP[o] = Ee0s[tl] * Pp0s[ul] * inv;
        if (u < U - 1) {
            const float eel = __expf(em[((size_t)b * T + t) * V + lbls[ul]]);
            labelP[o] = eel * Ppls[ul] * inv;
        }
    }
}

// ---------------------------------------------------------------------------
// K2: anti-diagonal alpha, probability domain (verbatim R12 — verified).
// ---------------------------------------------------------------------------
__global__ __launch_bounds__(256) void alpha_kernel(
    const float* __restrict__ blankP, const float* __restrict__ labelP,
    const int* __restrict__ in_len, const int* __restrict__ lab_len,
    float* __restrict__ out)
{
    __shared__ float2 QI[ROWS * U];   // QI[r][u] = {blank(r-1,u), label(r,u-1)}

    const int b   = blockIdx.x;
    const int tid = threadIdx.x;

    const float* gb = blankP + (size_t)b * T * U;
    const float* gl = labelP + (size_t)b * T * U;
    for (int i = tid; i < ROWS * U; i += 256) {
        const int r = i >> 6, u = i & 63;
        const float x = (r >= 1 && r <= T) ? gb[(r - 1) * U + u] : 0.0f;
        const float y = (r <= T - 1 && u >= 1) ? gl[r * U + u - 1] : 0.0f;
        QI[i] = make_float2(x, y);
    }
    __syncthreads();
    if (tid >= 64) return;

    const int u  = tid;
    const int Tb = in_len[b];
    const int Ub = lab_len[b];
    const int dmax = (Tb - 1) + Ub;

    auto qidx = [&](int d) {
        int r = d - u;
        r = min(max(r, 0), T + 1);
        return r * U + u;
    };

    float A = (u == 0) ? 1.0f : 0.0f;
    int   off = 0;
    float aCap = 1.0f;
    int   offCap = 0;
    float sPend = 1.0f;
    int   ePend = 0;

    float2 c8[8], n8[8];
    #pragma unroll
    for (int j = 0; j < 8; ++j) c8[j] = QI[qidx(1 + j)];

    for (int d0 = 1; d0 <= 185; d0 += 8) {       // d = 1..192 (dmax <= 190)
        #pragma unroll
        for (int j = 0; j < 8; ++j) {
            n8[j] = QI[qidx(d0 + 8 + j)];        // prefetch 8 diagonals ahead
            A = fmaf(A, c8[j].x, dpp_shr1(A) * c8[j].y);
            if ((j & 3) == 3) {
                A *= sPend;                      // apply stale scale (exact pow2)
                off += ePend;
                const float mx = rdlane(wave_max63(A), 63);
                int e = ((__builtin_bit_cast(int, mx) >> 23) & 255) - 127;
                e = max(e, -96);
                sPend = __builtin_bit_cast(float, (157 - e) << 23);
                ePend = e - 30;
            }
            const bool cap = (d0 + j == dmax);
            aCap   = cap ? A   : aCap;
            offCap = cap ? off : offCap;
        }
        #pragma unroll
        for (int j = 0; j < 8; ++j) c8[j] = n8[j];
    }

    if (u == Ub) {
        const float bprob = QI[Tb * U + u].x;    // blank(Tb-1, Ub)
        out[b] = -(__log2f(aCap) + (float)offCap + __log2f(bprob)) * LN2;
    }
}

extern "C" void kernel_launch(void* const* d_in, const int* in_sizes, int n_in,
                              void* d_out, int out_size, void* d_ws, size_t ws_size,
                              hipStream_t stream) {
    const float* em      = (const float*)d_in[0];  // (B,T,V)
    const float* pr      = (const float*)d_in[1];  // (B,U,V)
    const int*   labels  = (const int*)d_in[2];    // (B,U-1)
    const int*   in_len  = (const int*)d_in[3];    // (B,)
    const int*   lab_len = (const int*)d_in[4];    // (B,)
    float* out = (float*)d_out;                    // (B,)

    float* blankP = (float*)d_ws;                    // B*T*U floats (probabilities)
    float* labelP = blankP + (size_t)B * T * U;      // B*T*U floats

    lp_kernel<<<B * 4, 512, 0, stream>>>(em, pr, labels, blankP, labelP);
    alpha_kernel<<<B, 256, 0, stream>>>(blankP, labelP, in_len, lab_len, out);
}

// Round 16
// 31.642 us; speedup vs baseline: 1.1497x; 1.1497x over previous
//
#include <hip/hip_runtime.h>

#define B 8
#define T 128
#define U 64
#define V 512
#define LN2 0.6931471805599453f

// ---- DPP wave-64 helpers (VALU pipe; gfx9/CDNA ctrl encodings) -------------
template<int CTRL, int ROWM>
__device__ __forceinline__ float dpp_movf(float x, int old_bits) {
    int r = __builtin_amdgcn_update_dpp(old_bits, __builtin_bit_cast(int, x),
                                        CTRL, ROWM, 0xF, false);
    return __builtin_bit_cast(float, r);
}
__device__ __forceinline__ float wave_sum63(float x) {
    x += dpp_movf<0x111, 0xF>(x, 0);   // row_shr:1
    x += dpp_movf<0x112, 0xF>(x, 0);   // row_shr:2
    x += dpp_movf<0x114, 0xF>(x, 0);   // row_shr:4
    x += dpp_movf<0x118, 0xF>(x, 0);   // row_shr:8
    x += dpp_movf<0x142, 0xA>(x, 0);   // row_bcast:15 -> rows 1,3
    x += dpp_movf<0x143, 0xC>(x, 0);   // row_bcast:31 -> rows 2,3
    return x;
}
__device__ __forceinline__ float wave_max63(float x) {
    const int NI = (int)0xff800000u;   // -inf
    x = fmaxf(x, dpp_movf<0x111, 0xF>(x, NI));
    x = fmaxf(x, dpp_movf<0x112, 0xF>(x, NI));
    x = fmaxf(x, dpp_movf<0x114, 0xF>(x, NI));
    x = fmaxf(x, dpp_movf<0x118, 0xF>(x, NI));
    x = fmaxf(x, dpp_movf<0x142, 0xA>(x, NI));
    x = fmaxf(x, dpp_movf<0x143, 0xC>(x, NI));
    return x;
}
__device__ __forceinline__ float rdlane(float x, int lane) {
    return __builtin_bit_cast(float,
        __builtin_amdgcn_readlane(__builtin_bit_cast(int, x), lane));
}
// wave shift right by 1: lane u <- lane u-1; lane 0 <- 0.0f
__device__ __forceinline__ float dpp_shr1(float x) {
    int r = __builtin_amdgcn_update_dpp(0, __builtin_bit_cast(int, x),
                                        0x138, 0xF, 0xF, false); // wave_shr:1
    return __builtin_bit_cast(float, r);
}

// ---------------------------------------------------------------------------
// K1: joint softmax, factorized + probability-domain output (R10 verbatim —
// best measured: 31.5 us total).
//   S[t,u] = dot(exp(e[t]-me), exp(p[u]-mp));  blankP = exp(e0-me)*Pexp[u][0]/S
//   labelP = exp(e[lbl]-me)*Pexp[u][lbl]/S
// Grid: 256 blocks = (b:8) x (tg:16) x (ug:2); 256 thr.  Pexp[32][512] = 64 KB.
// ---------------------------------------------------------------------------
__global__ __launch_bounds__(256) void lp_kernel(
    const float* __restrict__ em, const float* __restrict__ pr,
    const int* __restrict__ labels,
    float* __restrict__ blankP, float* __restrict__ labelP)
{
    __shared__ float Pexp[32][V];      // 64 KB

    const int bid  = blockIdx.x;
    const int ug   = bid & 1;
    const int tg   = (bid >> 1) & 15;
    const int b    = bid >> 5;
    const int lane = threadIdx.x & 63;
    const int wave = threadIdx.x >> 6;

    #pragma unroll 2
    for (int r = 0; r < 8; ++r) {
        const int ul = wave * 8 + r;
        const int gu = ug * 32 + ul;
        const float* prow = pr + ((size_t)b * U + gu) * V;
        const float4 xa = ((const float4*)prow)[lane];
        const float4 xb = ((const float4*)prow)[64 + lane];
        float m = fmaxf(fmaxf(fmaxf(xa.x, xa.y), fmaxf(xa.z, xa.w)),
                        fmaxf(fmaxf(xb.x, xb.y), fmaxf(xb.z, xb.w)));
        const float mp = rdlane(wave_max63(m), 63);
        float4 oa, ob;
        oa.x = __expf(xa.x - mp); oa.y = __expf(xa.y - mp);
        oa.z = __expf(xa.z - mp); oa.w = __expf(xa.w - mp);
        ob.x = __expf(xb.x - mp); ob.y = __expf(xb.y - mp);
        ob.z = __expf(xb.z - mp); ob.w = __expf(xb.w - mp);
        ((float4*)&Pexp[ul][0])[lane]      = oa;
        ((float4*)&Pexp[ul][0])[64 + lane] = ob;
    }
    __syncthreads();

    const int t0 = tg * 8 + wave * 2;
    const int t1 = t0 + 1;
    const float* er0 = em + ((size_t)b * T + t0) * V;
    const float* er1 = em + ((size_t)b * T + t1) * V;
    const float4 ea0 = ((const float4*)er0)[lane];
    const float4 eb0 = ((const float4*)er0)[64 + lane];
    const float4 ea1 = ((const float4*)er1)[lane];
    const float4 eb1 = ((const float4*)er1)[64 + lane];
    float m0 = fmaxf(fmaxf(fmaxf(ea0.x, ea0.y), fmaxf(ea0.z, ea0.w)),
                     fmaxf(fmaxf(eb0.x, eb0.y), fmaxf(eb0.z, eb0.w)));
    float m1 = fmaxf(fmaxf(fmaxf(ea1.x, ea1.y), fmaxf(ea1.z, ea1.w)),
                     fmaxf(fmaxf(eb1.x, eb1.y), fmaxf(eb1.z, eb1.w)));
    const float me0 = rdlane(wave_max63(m0), 63);
    const float me1 = rdlane(wave_max63(m1), 63);
    float E0[8], E1[8];
    E0[0] = __expf(ea0.x - me0); E0[1] = __expf(ea0.y - me0);
    E0[2] = __expf(ea0.z - me0); E0[3] = __expf(ea0.w - me0);
    E0[4] = __expf(eb0.x - me0); E0[5] = __expf(eb0.y - me0);
    E0[6] = __expf(eb0.z - me0); E0[7] = __expf(eb0.w - me0);
    E1[0] = __expf(ea1.x - me1); E1[1] = __expf(ea1.y - me1);
    E1[2] = __expf(ea1.z - me1); E1[3] = __expf(ea1.w - me1);
    E1[4] = __expf(eb1.x - me1); E1[5] = __expf(eb1.y - me1);
    E1[6] = __expf(eb1.z - me1); E1[7] = __expf(eb1.w - me1);

    float S0 = 1.0f, S1 = 1.0f;
    #pragma unroll 2
    for (int ul = 0; ul < 32; ++ul) {
        const float4 pa = ((const float4*)&Pexp[ul][0])[lane];
        const float4 pb = ((const float4*)&Pexp[ul][0])[64 + lane];
        float p0 = E0[0] * pa.x;
        p0 = fmaf(E0[1], pa.y, p0); p0 = fmaf(E0[2], pa.z, p0);
        p0 = fmaf(E0[3], pa.w, p0); p0 = fmaf(E0[4], pb.x, p0);
        p0 = fmaf(E0[5], pb.y, p0); p0 = fmaf(E0[6], pb.z, p0);
        p0 = fmaf(E0[7], pb.w, p0);
        float p1 = E1[0] * pa.x;
        p1 = fmaf(E1[1], pa.y, p1); p1 = fmaf(E1[2], pa.z, p1);
        p1 = fmaf(E1[3], pa.w, p1); p1 = fmaf(E1[4], pb.x, p1);
        p1 = fmaf(E1[5], pb.y, p1); p1 = fmaf(E1[6], pb.z, p1);
        p1 = fmaf(E1[7], pb.w, p1);
        const float s0 = rdlane(wave_sum63(p0), 63);
        const float s1 = rdlane(wave_sum63(p1), 63);
        if (lane == ul) { S0 = s0; S1 = s1; }
    }

    if (lane < 32) {
        const int gu = ug * 32 + lane;
        const float Ppb = Pexp[lane][0];
        const float r0 = 1.0f / S0, r1 = 1.0f / S1;
        const float ebl0 = __expf(er0[0] - me0);
        const float ebl1 = __expf(er1[0] - me1);
        const size_t o0 = ((size_t)b * T + t0) * U + gu;
        const size_t o1 = o0 + U;
        blankP[o0] = ebl0 * Ppb * r0;
        blankP[o1] = ebl1 * Ppb * r1;
        if (gu < U - 1) {
            const int lb = labels[b * (U - 1) + gu];
            const float Ppl = Pexp[lane][lb];
            labelP[o0] = __expf(er0[lb] - me0) * Ppl * r0;
            labelP[o1] = __expf(er1[lb] - me1) * Ppl * r1;
        }
    }
}

// ---------------------------------------------------------------------------
// K2: anti-diagonal alpha recursion in PROBABILITY domain (R10 verbatim).
//   A[u] <- A[u]*bk(t-1,u) + A[u-1]*lb(t,u-1)     (junk/pad cells are 0)
// left-neighbor via DPP wave_shr:1; exact pow2 rescale every 4 steps;
// LDS operands software-pipelined 8 diagonals ahead.
// ---------------------------------------------------------------------------
__global__ __launch_bounds__(256) void alpha_kernel(
    const float* __restrict__ blankP, const float* __restrict__ labelP,
    const int* __restrict__ in_len, const int* __restrict__ lab_len,
    float* __restrict__ out)
{
    __shared__ float blankQ[(T + 2) * U];  // row r = t+1; rows 0, T+1 = 0
    __shared__ float labelQ[T * U];        // labelQ[t][u] = labelP[t][u-1]; col0=0

    const int b   = blockIdx.x;
    const int tid = threadIdx.x;

    const float* gb = blankP + (size_t)b * T * U;
    const float* gl = labelP + (size_t)b * T * U;
    float4* sb = (float4*)(blankQ + U);
    const float4* gb4 = (const float4*)gb;
    for (int i = tid; i < (T * U) / 4; i += 256) sb[i] = gb4[i];
    if (tid < 2 * U) {
        const int r = (tid < U) ? 0 : (T + 1);
        blankQ[r * U + (tid & (U - 1))] = 0.0f;
    }
    for (int i = tid; i < T * U; i += 256)
        labelQ[i] = (i & (U - 1)) ? gl[i - 1] : 0.0f;
    __syncthreads();
    if (tid >= 64) return;

    const int u  = tid;
    const int Tb = in_len[b];
    const int Ub = lab_len[b];
    const int dmax = (Tb - 1) + Ub;

    auto ib = [&](int d) {                       // blank at (t-1, u), padded+clamped
        int tm = d - 1 - u;
        tm = min(max(tm, -1), T);
        return (tm + 1) * U + u;
    };
    auto il = [&](int d) {                       // label at (t, u-1), shifted+clamped
        int tc = d - u;
        tc = min(max(tc, 0), T - 1);
        return tc * U + u;
    };

    float A = (u == 0) ? 1.0f : 0.0f;            // alpha[0,0] = 1
    int   off = 0;                                // true alpha = A * 2^off
    float aCap = 1.0f;
    int   offCap = 0;

    float cb[8], cl[8], nb[8], nl[8];
    #pragma unroll
    for (int j = 0; j < 8; ++j) { cb[j] = blankQ[ib(1 + j)]; cl[j] = labelQ[il(1 + j)]; }

    for (int d0 = 1; d0 <= 185; d0 += 8) {       // d = 1..192 (dmax <= 190)
        #pragma unroll
        for (int j = 0; j < 8; ++j) {
            nb[j] = blankQ[ib(d0 + 8 + j)];      // prefetch next group
            nl[j] = labelQ[il(d0 + 8 + j)];
            const float left = dpp_shr1(A);
            A = fmaf(A, cb[j], left * cl[j]);
            if ((j & 3) == 3) {                  // rescale every 4 steps
                const float mx = rdlane(wave_max63(A), 63);
                int e = ((__builtin_bit_cast(int, mx) >> 23) & 255) - 127;
                e = max(e, -96);                 // keep 2^(30-e) representable
                A *= __builtin_bit_cast(float, (157 - e) << 23);  // max -> ~2^30
                off += e - 30;
            }
            const bool cap = (d0 + j == dmax);
            aCap   = cap ? A   : aCap;
            offCap = cap ? off : offCap;
        }
        #pragma unroll
        for (int j = 0; j < 8; ++j) { cb[j] = nb[j]; cl[j] = nl[j]; }
    }

    if (u == Ub) {
        const float bprob = blankQ[Tb * U + u];  // blank at (Tb-1, Ub)
        const float v = __log2f(aCap) + (float)offCap + __log2f(bprob);
        out[b] = -v * LN2;
    }
}

extern "C" void kernel_launch(void* const* d_in, const int* in_sizes, int n_in,
                              void* d_out, int out_size, void* d_ws, size_t ws_size,
                              hipStream_t stream) {
    const float* em      = (const float*)d_in[0];  // (B,T,V)
    const float* pr      = (const float*)d_in[1];  // (B,U,V)
    const int*   labels  = (const int*)d_in[2];    // (B,U-1)
    const int*   in_len  = (const int*)d_in[3];    // (B,)
    const int*   lab_len = (const int*)d_in[4];    // (B,)
    float* out = (float*)d_out;                    // (B,)

    float* blankP = (float*)d_ws;                    // B*T*U floats (probabilities)
    float* labelP = blankP + (size_t)B * T * U;      // B*T*U floats

    lp_kernel<<<B * T / 4, 256, 0, stream>>>(em, pr, labels, blankP, labelP);
    alpha_kernel<<<B, 256, 0, stream>>>(blankP, labelP, in_len, lab_len, out);
}